// Round 1
// baseline (598.167 us; speedup 1.0000x reference)
//
#include <hip/hip_runtime.h>

#define NB  16
#define SQ  2048
#define SK  2048
#define DD  128

typedef unsigned short ushort_t;
typedef __attribute__((ext_vector_type(8))) short          bf16x8;
typedef __attribute__((ext_vector_type(8))) unsigned short us8;
typedef __attribute__((ext_vector_type(4))) float          f32x4;

__device__ __forceinline__ unsigned short f2bf(float x) {
  unsigned u = __builtin_bit_cast(unsigned, x);
  u += 0x7FFFu + ((u >> 16) & 1u);          // RNE truncate to bf16
  return (unsigned short)(u >> 16);
}

__device__ __forceinline__ void gload16(const void* g, void* l) {
  __builtin_amdgcn_global_load_lds(
      (__attribute__((address_space(1))) void*)(g),
      (__attribute__((address_space(3))) void*)(l), 16, 0, 0);
}

// ---------------- fp32 -> bf16 convert (8 elems/thread) ----------------
__global__ __launch_bounds__(256) void cvt_kernel(const float* __restrict__ s,
                                                  ushort_t* __restrict__ d, int n8) {
  int i = blockIdx.x * 256 + threadIdx.x;
  if (i >= n8) return;
  const float4* sp = (const float4*)s;
  float4 a = sp[2 * i];
  float4 b = sp[2 * i + 1];
  us8 o;
  o[0] = f2bf(a.x); o[1] = f2bf(a.y); o[2] = f2bf(a.z); o[3] = f2bf(a.w);
  o[4] = f2bf(b.x); o[5] = f2bf(b.y); o[6] = f2bf(b.z); o[7] = f2bf(b.w);
  *(us8*)(d + (size_t)i * 8) = o;
}

// ---------------- fused attention ----------------
// grid: 256 blocks (16 batches x 16 q-blocks of 128 rows), 512 threads (8 waves, 2x4)
__global__ __launch_bounds__(512, 2)
void attn_kernel(const ushort_t* __restrict__ Qb, const ushort_t* __restrict__ Kb,
                 const ushort_t* __restrict__ Vb, const int* __restrict__ mask,
                 float* __restrict__ octx, float* __restrict__ oattn)
{
  // all tiles XOR-swizzled: 16B chunk index ^= (row & 7)
  __shared__ ushort_t lQ[128 * 128];   // [qrow][d]
  __shared__ ushort_t lK[128 * 128];   // [kcol][d]
  __shared__ ushort_t lV[128 * 128];   // transposed: [dv][k]
  __shared__ ushort_t lP[128 * 128];   // [qrow][k]  (bf16 weights for PV)
  __shared__ float    rsum[128];

  const int tid  = threadIdx.x;
  const int lane = tid & 63;
  const int wid  = tid >> 6;
  const int g    = lane >> 4;   // 0..3
  const int c    = lane & 15;   // 0..15
  const int wm   = wid >> 2;    // 0..1  (64 q-rows each)
  const int wn   = wid & 3;     // 0..3  (32 cols each)

  const int b  = blockIdx.x >> 4;
  const int qb = (blockIdx.x & 15) << 7;

  if (tid < 128) rsum[tid] = 0.0f;

  // stage Q once (pre-swizzled source so linear global_load_lds lands swizzled)
#pragma unroll
  for (int it = 0; it < 4; ++it) {
    int seg = it * 8 + wid;
    int row = seg * 4 + g;
    int gc  = c ^ (row & 7);
    gload16(Qb + (((size_t)(b * SQ + qb + row)) << 7) + gc * 8, &lQ[seg * 512]);
  }

  const float SC = (float)(1.4426950408889634 * 0.08838834764831845); // log2e/sqrt(128)

  float ps[4][4];
#pragma unroll
  for (int m = 0; m < 4; ++m)
#pragma unroll
    for (int r = 0; r < 4; ++r) ps[m][r] = 0.0f;

  unsigned mbits[16];   // per-lane mask bits per k-tile (scratch: 1 dword/tile, cold)

  // ---------------- pass 1: row sums of masked exp ----------------
#pragma unroll 1
  for (int j = 0; j < 16; ++j) {
    __syncthreads();                       // previous tile's LDS reads done
#pragma unroll
    for (int it = 0; it < 4; ++it) {
      int seg = it * 8 + wid;
      int row = seg * 4 + g;
      int gc  = c ^ (row & 7);
      gload16(Kb + (((size_t)(b * SK + j * 128 + row)) << 7) + gc * 8, &lK[seg * 512]);
    }
    __syncthreads();                       // K staged (full drain)

    // mask loads issued here, consumed after the MFMA loop (latency hidden)
    int mk[4][2][4];
    {
      const int* mb_ = mask + (size_t)b * SQ * SK + (size_t)qb * SK + (size_t)j * 128 + wn * 32 + c;
#pragma unroll
      for (int m = 0; m < 4; ++m)
#pragma unroll
        for (int r = 0; r < 4; ++r) {
          int row = wm * 64 + m * 16 + g * 4 + r;
#pragma unroll
          for (int n = 0; n < 2; ++n)
            mk[m][n][r] = mb_[(size_t)row * SK + n * 16];
        }
    }

    f32x4 sacc[4][2];
#pragma unroll
    for (int m = 0; m < 4; ++m)
#pragma unroll
      for (int n = 0; n < 2; ++n) sacc[m][n] = {0.f, 0.f, 0.f, 0.f};

#pragma unroll
    for (int ks = 0; ks < 4; ++ks) {
      bf16x8 af[4], bfr[2];
#pragma unroll
      for (int m = 0; m < 4; ++m) {
        int row = wm * 64 + m * 16 + c;
        int ch  = (ks * 4 + g) ^ (row & 7);
        af[m] = *(const bf16x8*)&lQ[row * 128 + ch * 8];
      }
#pragma unroll
      for (int n = 0; n < 2; ++n) {
        int kr = wn * 32 + n * 16 + c;
        int ch = (ks * 4 + g) ^ (kr & 7);
        bfr[n] = *(const bf16x8*)&lK[kr * 128 + ch * 8];
      }
#pragma unroll
      for (int m = 0; m < 4; ++m)
#pragma unroll
        for (int n = 0; n < 2; ++n)
          sacc[m][n] = __builtin_amdgcn_mfma_f32_16x16x32_bf16(af[m], bfr[n], sacc[m][n], 0, 0, 0);
    }

    unsigned mb = 0u;
#pragma unroll
    for (int m = 0; m < 4; ++m)
#pragma unroll
      for (int n = 0; n < 2; ++n)
#pragma unroll
        for (int r = 0; r < 4; ++r) {
          bool keep = (mk[m][n][r] != 0);
          float e = keep ? exp2f(sacc[m][n][r] * SC) : 0.0f;
          ps[m][r] += e;
          if (keep) mb |= (1u << (m * 8 + n * 4 + r));
        }
    mbits[j] = mb;
  }

  // reduce row sums across the 16 col-lanes, then across the 4 col-waves
#pragma unroll
  for (int m = 0; m < 4; ++m)
#pragma unroll
    for (int r = 0; r < 4; ++r) {
      float v = ps[m][r];
      v += __shfl_xor(v, 1, 64);
      v += __shfl_xor(v, 2, 64);
      v += __shfl_xor(v, 4, 64);
      v += __shfl_xor(v, 8, 64);
      ps[m][r] = v;
    }
  if (c == 0) {
#pragma unroll
    for (int m = 0; m < 4; ++m)
#pragma unroll
      for (int r = 0; r < 4; ++r)
        atomicAdd(&rsum[wm * 64 + m * 16 + g * 4 + r], ps[m][r]);
  }
  __syncthreads();
  float invl[4][4];
#pragma unroll
  for (int m = 0; m < 4; ++m)
#pragma unroll
    for (int r = 0; r < 4; ++r)
      invl[m][r] = 1.0f / rsum[wm * 64 + m * 16 + g * 4 + r];

  // ---------------- pass 2: recompute S, write P, accumulate context ----------------
  f32x4 oacc[4][2];
#pragma unroll
  for (int m = 0; m < 4; ++m)
#pragma unroll
    for (int n = 0; n < 2; ++n) oacc[m][n] = {0.f, 0.f, 0.f, 0.f};

#pragma unroll 1
  for (int j = 0; j < 16; ++j) {
    __syncthreads();                       // prev S/PV reads of lK/lV/lP done
#pragma unroll
    for (int it = 0; it < 4; ++it) {
      int seg = it * 8 + wid;
      int row = seg * 4 + g;
      int gc  = c ^ (row & 7);
      gload16(Kb + (((size_t)(b * SK + j * 128 + row)) << 7) + gc * 8, &lK[seg * 512]);
    }
    // V staged transposed ([dv][k]) via regs, row-pair packed b32 writes, swizzled
#pragma unroll
    for (int it = 0; it < 2; ++it) {
      int cc = it * 8 + wid;
      int rp = lane;
      const ushort_t* vs = Vb + (((size_t)(b * SK + j * 128 + rp * 2)) << 7) + cc * 8;
      us8 va  = *(const us8*)vs;
      us8 vb2 = *(const us8*)(vs + 128);
#pragma unroll
      for (int i = 0; i < 8; ++i) {
        int col = cc * 8 + i;
        unsigned pk = (unsigned)va[i] | ((unsigned)vb2[i] << 16);
        int off = col * 256 + (((rp >> 2) ^ (col & 7)) << 4) + ((rp & 3) << 2);
        *(unsigned*)((char*)lV + off) = pk;
      }
    }
    __syncthreads();                       // K + Vt staged

    f32x4 sacc[4][2];
#pragma unroll
    for (int m = 0; m < 4; ++m)
#pragma unroll
      for (int n = 0; n < 2; ++n) sacc[m][n] = {0.f, 0.f, 0.f, 0.f};

#pragma unroll
    for (int ks = 0; ks < 4; ++ks) {
      bf16x8 af[4], bfr[2];
#pragma unroll
      for (int m = 0; m < 4; ++m) {
        int row = wm * 64 + m * 16 + c;
        int ch  = (ks * 4 + g) ^ (row & 7);
        af[m] = *(const bf16x8*)&lQ[row * 128 + ch * 8];
      }
#pragma unroll
      for (int n = 0; n < 2; ++n) {
        int kr = wn * 32 + n * 16 + c;
        int ch = (ks * 4 + g) ^ (kr & 7);
        bfr[n] = *(const bf16x8*)&lK[kr * 128 + ch * 8];
      }
#pragma unroll
      for (int m = 0; m < 4; ++m)
#pragma unroll
        for (int n = 0; n < 2; ++n)
          sacc[m][n] = __builtin_amdgcn_mfma_f32_16x16x32_bf16(af[m], bfr[n], sacc[m][n], 0, 0, 0);
    }

    // normalized weights: bf16 into lP (swizzled), f32 kept for global store
    unsigned mb = mbits[j];
    float wv[4][2][4];
#pragma unroll
    for (int m = 0; m < 4; ++m)
#pragma unroll
      for (int n = 0; n < 2; ++n)
#pragma unroll
        for (int r = 0; r < 4; ++r) {
          float w = ((mb >> (m * 8 + n * 4 + r)) & 1u)
                        ? exp2f(sacc[m][n][r] * SC) * invl[m][r] : 0.0f;
          wv[m][n][r] = w;
          int row = wm * 64 + m * 16 + g * 4 + r;
          int col = wn * 32 + n * 16 + c;
          int off = row * 256 + ((((col >> 3) ^ (row & 7))) << 4) + ((col & 7) << 1);
          *(ushort_t*)((char*)lP + off) = f2bf(w);
        }
    __syncthreads();                       // lP complete

    // global P stores issued now; they drain during / after the PV MFMAs
#pragma unroll
    for (int m = 0; m < 4; ++m)
#pragma unroll
      for (int n = 0; n < 2; ++n)
#pragma unroll
        for (int r = 0; r < 4; ++r) {
          int row = wm * 64 + m * 16 + g * 4 + r;
          int col = wn * 32 + n * 16 + c;
          oattn[(size_t)(b * SQ + qb + row) * SK + j * 128 + col] = wv[m][n][r];
        }

#pragma unroll
    for (int kk = 0; kk < 4; ++kk) {
      bf16x8 pf[4], vf[2];
#pragma unroll
      for (int m = 0; m < 4; ++m) {
        int row = wm * 64 + m * 16 + c;
        int ch  = (kk * 4 + g) ^ (row & 7);
        pf[m] = *(const bf16x8*)&lP[row * 128 + ch * 8];
      }
#pragma unroll
      for (int n = 0; n < 2; ++n) {
        int vcol = wn * 32 + n * 16 + c;
        int ch   = (kk * 4 + g) ^ (vcol & 7);
        vf[n] = *(const bf16x8*)&lV[vcol * 128 + ch * 8];
      }
#pragma unroll
      for (int m = 0; m < 4; ++m)
#pragma unroll
        for (int n = 0; n < 2; ++n)
          oacc[m][n] = __builtin_amdgcn_mfma_f32_16x16x32_bf16(pf[m], vf[n], oacc[m][n], 0, 0, 0);
    }
  }

  // epilogue: context
#pragma unroll
  for (int m = 0; m < 4; ++m)
#pragma unroll
    for (int n = 0; n < 2; ++n)
#pragma unroll
      for (int r = 0; r < 4; ++r) {
        int row = wm * 64 + m * 16 + g * 4 + r;
        int col = wn * 32 + n * 16 + c;
        octx[(size_t)(b * SQ + qb + row) * DD + col] = oacc[m][n][r];
      }
}

extern "C" void kernel_launch(void* const* d_in, const int* in_sizes, int n_in,
                              void* d_out, int out_size, void* d_ws, size_t ws_size,
                              hipStream_t stream) {
  const float* Q    = (const float*)d_in[0];
  const float* K    = (const float*)d_in[1];
  const float* V    = (const float*)d_in[2];
  const int*   mask = (const int*)d_in[3];

  float* ctx  = (float*)d_out;
  float* attn = (float*)d_out + (size_t)NB * SQ * DD;

  const size_t nElem = (size_t)NB * SQ * DD;       // 4,194,304 per tensor
  if (ws_size < 3 * nElem * sizeof(ushort_t)) return;  // fail fast (validation will flag)

  ushort_t* Qb = (ushort_t*)d_ws;
  ushort_t* Kb = Qb + nElem;
  ushort_t* Vb = Kb + nElem;

  const int n8 = (int)(nElem / 8);                 // 524,288
  dim3 cgrid((n8 + 255) / 256), cblk(256);
  cvt_kernel<<<cgrid, cblk, 0, stream>>>(Q, Qb, n8);
  cvt_kernel<<<cgrid, cblk, 0, stream>>>(K, Kb, n8);
  cvt_kernel<<<cgrid, cblk, 0, stream>>>(V, Vb, n8);

  attn_kernel<<<dim3(NB * (SQ / 128)), dim3(512), 0, stream>>>(Qb, Kb, Vb, mask, ctx, attn);
}

// Round 2
// 577.427 us; speedup vs baseline: 1.0359x; 1.0359x over previous
//
#include <hip/hip_runtime.h>

#define NB  16
#define SQ  2048
#define SK  2048
#define DD  128

typedef unsigned short ushort_t;
typedef __attribute__((ext_vector_type(8))) short          bf16x8;
typedef __attribute__((ext_vector_type(8))) unsigned short us8;
typedef __attribute__((ext_vector_type(4))) float          f32x4;

__device__ __forceinline__ unsigned short f2bf(float x) {
  unsigned u = __builtin_bit_cast(unsigned, x);
  u += 0x7FFFu + ((u >> 16) & 1u);          // RNE truncate to bf16
  return (unsigned short)(u >> 16);
}

__device__ __forceinline__ void gload16(const void* g, void* l) {
  __builtin_amdgcn_global_load_lds(
      (__attribute__((address_space(1))) void*)(g),
      (__attribute__((address_space(3))) void*)(l), 16, 0, 0);
}

// ---------------- fp32 -> bf16 convert, all three tensors in one launch ----------------
__global__ __launch_bounds__(256) void cvt3_kernel(const float* __restrict__ q,
                                                   const float* __restrict__ k,
                                                   const float* __restrict__ v,
                                                   ushort_t* __restrict__ dq,
                                                   ushort_t* __restrict__ dk,
                                                   ushort_t* __restrict__ dv,
                                                   int n8) {
  int i = blockIdx.x * 256 + threadIdx.x;
  const float* s; ushort_t* d; int r;
  if (i >= 2 * n8)      { s = v; d = dv; r = i - 2 * n8; }
  else if (i >= n8)     { s = k; d = dk; r = i - n8; }
  else                  { s = q; d = dq; r = i; }
  const float4* sp = (const float4*)s;
  float4 a = sp[2 * r];
  float4 b = sp[2 * r + 1];
  us8 o;
  o[0] = f2bf(a.x); o[1] = f2bf(a.y); o[2] = f2bf(a.z); o[3] = f2bf(a.w);
  o[4] = f2bf(b.x); o[5] = f2bf(b.y); o[6] = f2bf(b.z); o[7] = f2bf(b.w);
  *(us8*)(d + (size_t)r * 8) = o;
}

// ---------------- fused attention ----------------
// 512 blocks (16 batches x 32 q-blocks of 64 rows), 512 threads (8 waves, 2x4)
// LDS ~56.5 KB + VGPR<=128  => 2 blocks/CU resident (cross-block latency hiding)
__global__ __launch_bounds__(512, 4)
void attn_kernel(const ushort_t* __restrict__ Qb, const ushort_t* __restrict__ Kb,
                 const ushort_t* __restrict__ Vb, const int* __restrict__ mask,
                 float* __restrict__ octx, float* __restrict__ oattn)
{
  // XOR-swizzled tiles: 16B chunk index ^= (row & 7)
  __shared__ ushort_t lQ[64 * 128];     // 16 KB  [qrow][d]
  __shared__ ushort_t lKV[128 * 128];   // 32 KB  pass1: K[128k][128d]; pass2: K[64k][128d] + V^T[128dv][64k]
  __shared__ ushort_t lP[64 * 64];      //  8 KB  [qrow][k]
  __shared__ float    rsum[64];

  const int tid  = threadIdx.x;
  const int lane = tid & 63;
  const int wid  = tid >> 6;
  const int g    = lane >> 4;   // 0..3
  const int c    = lane & 15;   // 0..15
  const int wm   = wid >> 2;    // 0..1  (32 q-rows each)
  const int wn   = wid & 3;     // 0..3

  // bijective XCD swizzle (512 % 8 == 0): same-XCD blocks share a batch's K/V in L2
  const int orig = (blockIdx.x & 7) * 64 + (blockIdx.x >> 3);
  const int b    = orig >> 5;
  const int qb   = (orig & 31) << 6;

  if (tid < 64) rsum[tid] = 0.0f;

  // stage Q once (pre-swizzled source, linear global_load_lds dest)
#pragma unroll
  for (int it = 0; it < 2; ++it) {
    int seg = it * 8 + wid;
    int row = seg * 4 + g;
    int gc  = c ^ (row & 7);
    gload16(Qb + (((size_t)(b * SQ + qb + row)) << 7) + gc * 8, &lQ[seg * 512]);
  }

  const float SC = (float)(1.4426950408889634 * 0.08838834764831845); // log2e/sqrt(128)

  float ps[2][4];
#pragma unroll
  for (int m = 0; m < 2; ++m)
#pragma unroll
    for (int r = 0; r < 4; ++r) ps[m][r] = 0.0f;

  unsigned mbits[8];   // 16 bits per pass1-tile (m2*n2*r4), two tiles per dword

  // ---------------- pass 1: row sums of masked exp (k-tile 128) ----------------
#pragma unroll 1
  for (int j = 0; j < 16; ++j) {
    __syncthreads();
#pragma unroll
    for (int it = 0; it < 4; ++it) {
      int seg = it * 8 + wid;
      int row = seg * 4 + g;
      int gc  = c ^ (row & 7);
      gload16(Kb + (((size_t)(b * SK + j * 128 + row)) << 7) + gc * 8, &lKV[seg * 512]);
    }
    __syncthreads();

    // mask loads issued now, consumed after the MFMA loop
    int mk[2][2][4];
    {
      const size_t base = (size_t)b * SQ * SK + (size_t)(qb + wm * 32) * SK + (size_t)j * 128;
#pragma unroll
      for (int m = 0; m < 2; ++m)
#pragma unroll
        for (int n = 0; n < 2; ++n)
#pragma unroll
          for (int r = 0; r < 4; ++r)
            mk[m][n][r] = mask[base + (size_t)(m * 16 + g * 4 + r) * SK + n * 64 + wn * 16 + c];
    }

    f32x4 sacc[2][2];
#pragma unroll
    for (int m = 0; m < 2; ++m)
#pragma unroll
      for (int n = 0; n < 2; ++n) sacc[m][n] = {0.f, 0.f, 0.f, 0.f};

#pragma unroll
    for (int ks = 0; ks < 4; ++ks) {
      bf16x8 af[2], bfr[2];
#pragma unroll
      for (int m = 0; m < 2; ++m) {
        int row = wm * 32 + m * 16 + c;
        int ch  = (ks * 4 + g) ^ (row & 7);
        af[m] = *(const bf16x8*)&lQ[row * 128 + ch * 8];
      }
#pragma unroll
      for (int n = 0; n < 2; ++n) {
        int kr = n * 64 + wn * 16 + c;
        int ch = (ks * 4 + g) ^ (kr & 7);
        bfr[n] = *(const bf16x8*)&lKV[kr * 128 + ch * 8];
      }
#pragma unroll
      for (int m = 0; m < 2; ++m)
#pragma unroll
        for (int n = 0; n < 2; ++n)
          sacc[m][n] = __builtin_amdgcn_mfma_f32_16x16x32_bf16(af[m], bfr[n], sacc[m][n], 0, 0, 0);
    }

    unsigned mb = 0u;
#pragma unroll
    for (int m = 0; m < 2; ++m)
#pragma unroll
      for (int n = 0; n < 2; ++n)
#pragma unroll
        for (int r = 0; r < 4; ++r) {
          bool keep = (mk[m][n][r] != 0);
          float e = keep ? exp2f(sacc[m][n][r] * SC) : 0.0f;
          ps[m][r] += e;
          if (keep) mb |= (1u << (m * 8 + n * 4 + r));
        }
    if (j & 1) mbits[j >> 1] |= (mb << 16);
    else       mbits[j >> 1] = mb;
  }

  // reduce over the 16 c-lanes, then across the 4 wn-waves via LDS atomics
#pragma unroll
  for (int m = 0; m < 2; ++m)
#pragma unroll
    for (int r = 0; r < 4; ++r) {
      float v = ps[m][r];
      v += __shfl_xor(v, 1, 64);
      v += __shfl_xor(v, 2, 64);
      v += __shfl_xor(v, 4, 64);
      v += __shfl_xor(v, 8, 64);
      ps[m][r] = v;
    }
  if (c == 0) {
#pragma unroll
    for (int m = 0; m < 2; ++m)
#pragma unroll
      for (int r = 0; r < 4; ++r)
        atomicAdd(&rsum[wm * 32 + m * 16 + g * 4 + r], ps[m][r]);
  }
  __syncthreads();
  float invl[2][4];
#pragma unroll
  for (int m = 0; m < 2; ++m)
#pragma unroll
    for (int r = 0; r < 4; ++r)
      invl[m][r] = 1.0f / rsum[wm * 32 + m * 16 + g * 4 + r];

  // ---------------- pass 2: recompute S, write P, accumulate context (k-tile 64) ----------------
  f32x4 oacc[2][2];
#pragma unroll
  for (int m = 0; m < 2; ++m)
#pragma unroll
    for (int n = 0; n < 2; ++n) oacc[m][n] = {0.f, 0.f, 0.f, 0.f};

  ushort_t* lV = lKV + 64 * 128;   // second 16 KB half: V^T[128dv][64k]

#pragma unroll 1
  for (int j2 = 0; j2 < 32; ++j2) {
    __syncthreads();
    // K tile 64x128
#pragma unroll
    for (int it = 0; it < 2; ++it) {
      int seg = it * 8 + wid;
      int row = seg * 4 + g;
      int gc  = c ^ (row & 7);
      gload16(Kb + (((size_t)(b * SK + j2 * 64 + row)) << 7) + gc * 8, &lKV[seg * 512]);
    }
    // V^T staged via regs (row-pair packed b32 writes, swizzled)
    {
      int rp = tid & 31;          // row pair: k rows 2rp, 2rp+1
      int cs = tid >> 5;          // 0..15 -> dv cols cs*8..cs*8+7
      const ushort_t* vs = Vb + (((size_t)(b * SK + j2 * 64 + rp * 2)) << 7) + cs * 8;
      us8 va  = *(const us8*)vs;
      us8 vb2 = *(const us8*)(vs + 128);
#pragma unroll
      for (int i = 0; i < 8; ++i) {
        int col = cs * 8 + i;     // dv
        unsigned pk = (unsigned)va[i] | ((unsigned)vb2[i] << 16);
        int off = col * 128 + (((rp >> 2) ^ (col & 7)) << 4) + ((rp & 3) << 2);
        *(unsigned*)((char*)lV + off) = pk;
      }
    }
    __syncthreads();

    // S = Q K^T over d=128 (4 MFMA K-steps), per-wave strip of 16 k-cols
    f32x4 sacc[2];
    sacc[0] = {0.f, 0.f, 0.f, 0.f};
    sacc[1] = {0.f, 0.f, 0.f, 0.f};
#pragma unroll
    for (int ks = 0; ks < 4; ++ks) {
      bf16x8 af[2], bfr;
#pragma unroll
      for (int m = 0; m < 2; ++m) {
        int row = wm * 32 + m * 16 + c;
        int ch  = (ks * 4 + g) ^ (row & 7);
        af[m] = *(const bf16x8*)&lQ[row * 128 + ch * 8];
      }
      {
        int kr = wn * 16 + c;
        int ch = (ks * 4 + g) ^ (kr & 7);
        bfr = *(const bf16x8*)&lKV[kr * 128 + ch * 8];
      }
#pragma unroll
      for (int m = 0; m < 2; ++m)
        sacc[m] = __builtin_amdgcn_mfma_f32_16x16x32_bf16(af[m], bfr, sacc[m], 0, 0, 0);
    }

    // normalized weights -> lP (bf16, swizzled) + global store (f32)
    unsigned mw = mbits[j2 >> 2];
#pragma unroll
    for (int m = 0; m < 2; ++m)
#pragma unroll
      for (int r = 0; r < 4; ++r) {
        int bit = ((j2 >> 1) & 1) * 16 + m * 8 + (j2 & 1) * 4 + r;
        float w = ((mw >> bit) & 1u) ? exp2f(sacc[m][r] * SC) * invl[m][r] : 0.0f;
        int row = wm * 32 + m * 16 + g * 4 + r;
        int col = wn * 16 + c;
        int off = row * 128 + ((((col >> 3) ^ (row & 7)) & 7) << 4) + ((col & 7) << 1);
        *(ushort_t*)((char*)lP + off) = f2bf(w);
        oattn[(size_t)(b * SQ + qb + row) * SK + j2 * 64 + col] = w;
      }
    __syncthreads();

    // PV: O += P[64q x 64k] * V[64k x 128dv]  (2 MFMA K-steps)
#pragma unroll
    for (int kk = 0; kk < 2; ++kk) {
      bf16x8 pf[2], vf[2];
#pragma unroll
      for (int m = 0; m < 2; ++m) {
        int row = wm * 32 + m * 16 + c;
        int ch  = (kk * 4 + g) ^ (row & 7);
        pf[m] = *(const bf16x8*)&lP[row * 64 + ch * 8];
      }
#pragma unroll
      for (int n = 0; n < 2; ++n) {
        int dv = wn * 32 + n * 16 + c;
        int ch = (kk * 4 + g) ^ (dv & 7);
        vf[n] = *(const bf16x8*)&lV[dv * 64 + ch * 8];
      }
#pragma unroll
      for (int m = 0; m < 2; ++m)
#pragma unroll
        for (int n = 0; n < 2; ++n)
          oacc[m][n] = __builtin_amdgcn_mfma_f32_16x16x32_bf16(pf[m], vf[n], oacc[m][n], 0, 0, 0);
    }
  }

  // epilogue: context
#pragma unroll
  for (int m = 0; m < 2; ++m)
#pragma unroll
    for (int n = 0; n < 2; ++n)
#pragma unroll
      for (int r = 0; r < 4; ++r) {
        int row = wm * 32 + m * 16 + g * 4 + r;
        int col = wn * 32 + n * 16 + c;
        octx[(size_t)(b * SQ + qb + row) * DD + col] = oacc[m][n][r];
      }
}

extern "C" void kernel_launch(void* const* d_in, const int* in_sizes, int n_in,
                              void* d_out, int out_size, void* d_ws, size_t ws_size,
                              hipStream_t stream) {
  const float* Q    = (const float*)d_in[0];
  const float* K    = (const float*)d_in[1];
  const float* V    = (const float*)d_in[2];
  const int*   mask = (const int*)d_in[3];

  float* ctx  = (float*)d_out;
  float* attn = (float*)d_out + (size_t)NB * SQ * DD;

  const size_t nElem = (size_t)NB * SQ * DD;       // 4,194,304 per tensor
  if (ws_size < 3 * nElem * sizeof(ushort_t)) return;

  ushort_t* Qb = (ushort_t*)d_ws;
  ushort_t* Kb = Qb + nElem;
  ushort_t* Vb = Kb + nElem;

  const int n8 = (int)(nElem / 8);                 // 524,288 (multiple of 256)
  cvt3_kernel<<<dim3(3 * n8 / 256), dim3(256), 0, stream>>>(Q, K, V, Qb, Kb, Vb, n8);

  attn_kernel<<<dim3(NB * (SQ / 64)), dim3(512), 0, stream>>>(Qb, Kb, Vb, mask, ctx, attn);
}